// Round 22
// baseline (25.523 us; speedup 1.0000x reference)
//
#include <hip/hip_runtime.h>

#define G 32
#define G2 (G*G)
#define G3 (G*G*G)
#define NPTS 50000
#define NB 8
#define NC 16
#define CHUNK 256
#define NCHUNK_PER_B 196             // ceil(50000/256)
#define CAP 16384                    // per-(b,plane) payload capacity (uniform max ~3.3k)

// ws layout (bytes):
//   [0, 1024)    head[256] (int, zeroed by memset node; ends as bin count)
//   [4096, ...)  payload u64[256][CAP]  (32 MB, contiguous per bin)
#define OFF_HEAD    0
#define OFF_PAYLOAD 4096

// 8-byte payload entry (identical encoding to R20):
//   [55:43] ax | [42:30] ay1 | [29:17] az1 | [16:12] iy1 | [11:7] iz1
//   [6] sy | [5] sz | [4] fr-1 | [3:0] fp32-exact d^2 gate mask (cy,cz)

// K1: 256-thread blocks (1568 total -> ~6/CU, balanced). Corner-resolve +
// gate + prune at bin time; plane-grouped LDS staging; one global atomicAdd
// per (block,plane) for the contiguous slot base; coalesced 8B copy-out.
__global__ __launch_bounds__(256) void ge_bin(const float* __restrict__ x,
                                              int* __restrict__ head,
                                              unsigned long long* __restrict__ payload) {
    __shared__ unsigned long long sp[2 * CHUNK];  // 4 KB staged entries
    __shared__ unsigned char spl[2 * CHUNK];
    __shared__ int h[G];
    __shared__ int offs[G + 1];
    __shared__ int gbase[G];

    const int tid = threadIdx.x;
    const int b   = blockIdx.y;
    const int n   = blockIdx.x * CHUNK + tid;
    const bool valid = n < NPTS;

    if (tid < G) h[tid] = 0;
    __syncthreads();

    unsigned long long e1 = 0, e2 = 0;
    int p1 = 0, p2 = 0, r1 = 0, r2 = 0;
    bool put1 = false, put2 = false;

    if (valid) {
        const float* xb = x + (size_t)b * 3 * NPTS;
        float rx = (xb[n]          + 0.5f) * 32.0f - 0.5f;
        float ry = (xb[NPTS + n]   + 0.5f) * 32.0f - 0.5f;
        float rz = (xb[2*NPTS + n] + 0.5f) * 32.0f - 0.5f;
        p1 = (int)fminf(fmaxf(floorf(rx), 0.0f), 31.0f);
        p2 = (int)fminf(fmaxf(ceilf (rx), 0.0f), 31.0f);

        float fy1 = fminf(fmaxf(floorf(ry), 0.0f), 31.0f);
        float fy2 = fminf(fmaxf(ceilf (ry), 0.0f), 31.0f);
        float fz1 = fminf(fmaxf(floorf(rz), 0.0f), 31.0f);
        float fz2 = fminf(fmaxf(ceilf (rz), 0.0f), 31.0f);
        float dy1 = ry - fy1, dy2 = ry - fy2;
        float dz1 = rz - fz1, dz2 = rz - fz2;
        float dy1s = dy1 * dy1, dy2s = dy2 * dy2;
        float dz1s = dz1 * dz1, dz2s = dz2 * dz2;

        int iy1 = (int)fy1, sy = (int)fy2 - iy1;
        int iz1 = (int)fz1, sz = (int)fz2 - iz1;
        int ay1 = (int)rintf(dy1 * 2048.0f) + 2048;
        int az1 = (int)rintf(dz1 * 2048.0f) + 2048;
        unsigned long long common =
              ((unsigned long long)(unsigned)ay1 << 30)
            | ((unsigned long long)(unsigned)az1 << 17)
            | ((unsigned long long)(unsigned)iy1 << 12)
            | ((unsigned long long)(unsigned)iz1 << 7)
            | ((unsigned long long)(unsigned)sy  << 6)
            | ((unsigned long long)(unsigned)sz  << 5);
        unsigned fr1 = (p1 == p2) ? 2u : 1u;  // ref double-counts collapsed x

        {   // plane p1 entry
            float dx = rx - (float)p1;
            float dx2 = dx * dx;
            float a0 = dx2 + dy1s, a1 = dx2 + dy2s;
            unsigned m = 0;
            if (a0 + dz1s < 0.7569f) m |= 1u;
            if (a0 + dz2s < 0.7569f) m |= 2u;
            if (a1 + dz1s < 0.7569f) m |= 4u;
            if (a1 + dz2s < 0.7569f) m |= 8u;
            if (m) {
                unsigned ax = (unsigned)((int)rintf(dx * 2048.0f) + 2048);
                e1 = ((unsigned long long)ax << 43) | common
                   | ((unsigned long long)(fr1 - 1u) << 4) | m;
                put1 = true;
                r1 = atomicAdd(&h[p1], 1);
            }
        }
        if (p2 != p1) {
            float dx = rx - (float)p2;
            float dx2 = dx * dx;
            float a0 = dx2 + dy1s, a1 = dx2 + dy2s;
            unsigned m = 0;
            if (a0 + dz1s < 0.7569f) m |= 1u;
            if (a0 + dz2s < 0.7569f) m |= 2u;
            if (a1 + dz1s < 0.7569f) m |= 4u;
            if (a1 + dz2s < 0.7569f) m |= 8u;
            if (m) {
                unsigned ax = (unsigned)((int)rintf(dx * 2048.0f) + 2048);
                e2 = ((unsigned long long)ax << 43) | common | m;  // fr=1
                put2 = true;
                r2 = atomicAdd(&h[p2], 1);
            }
        }
    }
    __syncthreads();

    if (tid == 0) {
        int run = 0;
        #pragma unroll
        for (int p = 0; p < G; ++p) { offs[p] = run; run += h[p]; }
        offs[G] = run;
    }
    __syncthreads();

    if (tid < G) {
        int c = h[tid];
        gbase[tid] = c ? atomicAdd(&head[b * G + tid], c) : 0;
    }
    if (put1) { int i1 = offs[p1] + r1; sp[i1] = e1; spl[i1] = (unsigned char)p1; }
    if (put2) { int i2 = offs[p2] + r2; sp[i2] = e2; spl[i2] = (unsigned char)p2; }
    __syncthreads();

    const int T = offs[G];
    unsigned long long* pb = payload;
    for (int e = tid; e < T; e += CHUNK) {
        int p = spl[e];
        size_t pos = (size_t)gbase[p] + (e - offs[p]);
        if (pos < CAP)
            pb[((size_t)b * G + p) * CAP + pos] = sp[e];
    }
}

// K2: flat contiguous per-bin run — coalesced reads, ~100% lane utilization;
// integer decode + masked packed u64 LDS atomics; fused 16-channel epilogue.
__global__ __launch_bounds__(1024) void ge_accum(const unsigned long long* __restrict__ payload,
                                                 const int* __restrict__ head,
                                                 const float* __restrict__ W,
                                                 const float* __restrict__ bias,
                                                 float* __restrict__ out) {
    __shared__ unsigned long long A[G2];   // 8 KB
    const int tid = threadIdx.x;
    const int bin = blockIdx.x;            // b*32+s
    const int b = bin >> 5, s = bin & 31;

    A[tid] = 0ull;
    __syncthreads();

    int cnt = head[bin];
    if (cnt > CAP) cnt = CAP;
    const unsigned long long* q = payload + (size_t)bin * CAP;

    for (int i = tid; i < cnt; i += 1024) {
        unsigned long long e = q[i];
        unsigned m   = (unsigned)e & 15u;
        unsigned fr  = 1u + (((unsigned)e >> 4) & 1u);
        int szi = ((int)e >> 5) & 1;
        int syi = ((int)e >> 6) & 1;
        int iz1 = ((int)e >> 7) & 31;
        int iy1 = ((int)e >> 12) & 31;
        unsigned az1 = (unsigned)(e >> 17) & 0x1FFFu;
        unsigned ay1 = (unsigned)(e >> 30) & 0x1FFFu;
        unsigned ax  = (unsigned)(e >> 43) & 0x1FFFu;

        unsigned long long base = ((unsigned long long)fr << 57)
                                | ((unsigned long long)(ax * fr) << 38);
        unsigned ayl = ay1 * fr, ayh = (ay1 - 2048u * syi) * fr;
        unsigned azl = az1 * fr, azh = (az1 - 2048u * szi) * fr;
        int cell = iy1 * G + iz1;

        if (m & 1u) atomicAdd(&A[cell],
            ((unsigned long long)ayl << 19) | azl | base);
        if (m & 2u) atomicAdd(&A[cell + szi],
            ((unsigned long long)ayl << 19) | azh | base);
        if (m & 4u) atomicAdd(&A[cell + G * syi],
            ((unsigned long long)ayh << 19) | azl | base);
        if (m & 8u) atomicAdd(&A[cell + G * syi + szi],
            ((unsigned long long)ayh << 19) | azh | base);
    }
    __syncthreads();

    const unsigned long long a = A[tid];
    const float cw  = (float)(unsigned)(a >> 57);
    const float fxs = (float)(unsigned)((a >> 38) & 0x7FFFFull);
    const float fys = (float)(unsigned)((a >> 19) & 0x7FFFFull);
    const float fzs = (float)(unsigned)( a         & 0x7FFFFull);
    const float kq = 1.0f / 2048.0f;
    const float sx = (fxs - 2048.0f * cw) * kq;
    const float sy = (fys - 2048.0f * cw) * kq;
    const float sz = (fzs - 2048.0f * cw) * kq;
    const float inv = 1.0f / fmaxf(cw, 1.0f);

    float* ob = out + (size_t)b * NC * G3 + (size_t)s * G2 + tid;
    #pragma unroll
    for (int ch = 0; ch < NC; ++ch) {
        float v = W[ch * 3 + 0] * sx + W[ch * 3 + 1] * sy + W[ch * 3 + 2] * sz
                + cw * bias[ch];
        ob[(size_t)ch * G3] = v * inv;
    }
}

// ---------- fallback: round-7 single kernel (used if ws too small) ----------
#define SEG 12288
#define QMAX SEG
__global__ __launch_bounds__(1024) void ge_fused(const float* __restrict__ x,
                                                 const float* __restrict__ W,
                                                 const float* __restrict__ bias,
                                                 float* __restrict__ out) {
    __shared__ float acc[G2][4];
    __shared__ int   q[QMAX];
    __shared__ int   qcount;
    const int b = blockIdx.x >> 5;
    const int s = blockIdx.x & 31;
    const float fs = (float)s;
    const int lane = threadIdx.x & 63;
    for (int i = threadIdx.x; i < G2 * 4; i += 1024) ((float*)acc)[i] = 0.0f;
    if (threadIdx.x == 0) qcount = 0;
    __syncthreads();
    const float* xb = x + (size_t)b * 3 * NPTS;
    for (int seg = 0; seg < NPTS; seg += SEG) {
        const int seg_end = (seg + SEG < NPTS) ? seg + SEG : NPTS;
        for (int base = seg; base < seg_end; base += 1024) {
            int n = base + threadIdx.x;
            bool pred = false; int tag = 0;
            if (n < seg_end) {
                float rx = (xb[n] + 0.5f) * 32.0f - 0.5f;
                int p1 = (int)fminf(fmaxf(floorf(rx), 0.0f), 31.0f);
                int p2 = (int)fminf(fmaxf(ceilf (rx), 0.0f), 31.0f);
                int reps = (p1 == s) + (p2 == s);
                pred = reps > 0;
                tag = n | (reps == 2 ? (int)0x80000000 : 0);
            }
            unsigned long long mask = __ballot(pred);
            int wcnt = __popcll(mask);
            if (wcnt) {
                int wbase = 0;
                if (lane == 0) wbase = atomicAdd(&qcount, wcnt);
                wbase = __shfl(wbase, 0);
                if (pred) q[wbase + __popcll(mask & ((1ULL << lane) - 1ULL))] = tag;
            }
        }
        __syncthreads();
        const int cnt = qcount;
        for (int i = threadIdx.x; i < cnt; i += 1024) {
            int e = q[i];
            int n = e & 0x7fffffff;
            float fr = (e < 0) ? 2.0f : 1.0f;
            float rx = (xb[n]          + 0.5f) * 32.0f - 0.5f;
            float ry = (xb[NPTS + n]   + 0.5f) * 32.0f - 0.5f;
            float rz = (xb[2*NPTS + n] + 0.5f) * 32.0f - 0.5f;
            float dx = rx - fs;
            float fy1 = fminf(fmaxf(floorf(ry), 0.0f), 31.0f);
            float fy2 = fminf(fmaxf(ceilf (ry), 0.0f), 31.0f);
            float fz1 = fminf(fmaxf(floorf(rz), 0.0f), 31.0f);
            float fz2 = fminf(fmaxf(ceilf (rz), 0.0f), 31.0f);
            #pragma unroll
            for (int cy = 0; cy < 2; ++cy) {
                float iy = cy ? fy2 : fy1;
                float dy = ry - iy;
                #pragma unroll
                for (int cz = 0; cz < 2; ++cz) {
                    float iz = cz ? fz2 : fz1;
                    float dz = rz - iz;
                    float d2 = dx * dx + dy * dy + dz * dz;
                    if (d2 < 0.7569f) {
                        int cell = (int)iy * G + (int)iz;
                        atomicAdd(&acc[cell][0], fr * dx);
                        atomicAdd(&acc[cell][1], fr * dy);
                        atomicAdd(&acc[cell][2], fr * dz);
                        atomicAdd(&acc[cell][3], fr);
                    }
                }
            }
        }
        __syncthreads();
        if (threadIdx.x == 0) qcount = 0;
        __syncthreads();
    }
    int cell = threadIdx.x;
    float sx = acc[cell][0], sy = acc[cell][1], sz = acc[cell][2], cnt = acc[cell][3];
    float inv = 1.0f / fmaxf(cnt, 1.0f);
    float* ob = out + (size_t)b * NC * G3 + (size_t)s * G2 + cell;
    #pragma unroll
    for (int c = 0; c < NC; ++c) {
        float v = W[c * 3 + 0] * sx + W[c * 3 + 1] * sy + W[c * 3 + 2] * sz
                + cnt * bias[c];
        ob[(size_t)c * G3] = v * inv;
    }
}

extern "C" void kernel_launch(void* const* d_in, const int* in_sizes, int n_in,
                              void* d_out, int out_size, void* d_ws, size_t ws_size,
                              hipStream_t stream) {
    const float* x    = (const float*)d_in[0];   // [8,3,50000]
    const float* W    = (const float*)d_in[1];   // [16,3]
    const float* bias = (const float*)d_in[2];   // [16]
    float* out = (float*)d_out;                  // [8,16,32,32,32]

    const size_t need = OFF_PAYLOAD + (size_t)NB * G * CAP * sizeof(unsigned long long);
    if (ws_size >= need) {
        char* wsb = (char*)d_ws;
        int* head = (int*)(wsb + OFF_HEAD);
        unsigned long long* payload = (unsigned long long*)(wsb + OFF_PAYLOAD);

        hipMemsetAsync(head, 0, NB * G * sizeof(int), stream);
        ge_bin  <<<dim3(NCHUNK_PER_B, NB), CHUNK, 0, stream>>>(x, head, payload);
        ge_accum<<<NB * G, 1024, 0, stream>>>(payload, head, W, bias, out);
    } else {
        ge_fused<<<NB * G, 1024, 0, stream>>>(x, W, bias, out);
    }
}

// Round 23
// 19.071 us; speedup vs baseline: 1.3383x; 1.3383x over previous
//
#include <hip/hip_runtime.h>

#define G 32
#define G2 (G*G)
#define G3 (G*G*G)
#define NPTS 50000
#define NB 8
#define NC 16
#define NCHUNK_PER_B 49              // ceil(50000/1024)
#define NCHUNK (NB*NCHUNK_PER_B)     // 392
#define SUBCAP 1024                  // max entries per (chunk,plane): <=1 per point

// ws layout (bytes) — nothing needs pre-zeroing, no global atomics anywhere:
//   [0, 50176)    hist[392][32] (int)
//   [65536, ...)  payload u64[392][32][1024]  (98 MiB, sparsely touched)
#define OFF_HIST    0
#define OFF_PAYLOAD 65536

// 8-byte payload entry (identical encoding to R20):
//   [55:43] ax | [42:30] ay1 | [29:17] az1 | [16:12] iy1 | [11:7] iz1
//   [6] sy | [5] sz | [4] fr-1 | [3:0] fp32-exact d^2 gate mask (cy,cz)

// K1 (unchanged from R20, measured ~8us): bin one 1024-point chunk;
// corner-resolve + gate + prune; plane-grouped LDS staging; coalesced copy-out.
__global__ __launch_bounds__(1024) void ge_bin(const float* __restrict__ x,
                                               int* __restrict__ hist,
                                               unsigned long long* __restrict__ payload) {
    __shared__ unsigned long long sp[2048];   // 16 KB staged entries
    __shared__ unsigned char spl[2048];
    __shared__ int h[G];
    __shared__ int offs[G + 1];

    const int tid = threadIdx.x;
    const int b   = blockIdx.y;
    const int c   = b * NCHUNK_PER_B + blockIdx.x;
    const int n   = blockIdx.x * 1024 + tid;
    const bool valid = n < NPTS;

    if (tid < G) h[tid] = 0;
    __syncthreads();

    unsigned long long e1 = 0, e2 = 0;
    int p1 = 0, p2 = 0, r1 = 0, r2 = 0;
    bool put1 = false, put2 = false;

    if (valid) {
        const float* xb = x + (size_t)b * 3 * NPTS;
        float rx = (xb[n]          + 0.5f) * 32.0f - 0.5f;
        float ry = (xb[NPTS + n]   + 0.5f) * 32.0f - 0.5f;
        float rz = (xb[2*NPTS + n] + 0.5f) * 32.0f - 0.5f;
        p1 = (int)fminf(fmaxf(floorf(rx), 0.0f), 31.0f);
        p2 = (int)fminf(fmaxf(ceilf (rx), 0.0f), 31.0f);

        float fy1 = fminf(fmaxf(floorf(ry), 0.0f), 31.0f);
        float fy2 = fminf(fmaxf(ceilf (ry), 0.0f), 31.0f);
        float fz1 = fminf(fmaxf(floorf(rz), 0.0f), 31.0f);
        float fz2 = fminf(fmaxf(ceilf (rz), 0.0f), 31.0f);
        float dy1 = ry - fy1, dy2 = ry - fy2;
        float dz1 = rz - fz1, dz2 = rz - fz2;
        float dy1s = dy1 * dy1, dy2s = dy2 * dy2;
        float dz1s = dz1 * dz1, dz2s = dz2 * dz2;

        int iy1 = (int)fy1, sy = (int)fy2 - iy1;
        int iz1 = (int)fz1, sz = (int)fz2 - iz1;
        int ay1 = (int)rintf(dy1 * 2048.0f) + 2048;
        int az1 = (int)rintf(dz1 * 2048.0f) + 2048;
        unsigned long long common =
              ((unsigned long long)(unsigned)ay1 << 30)
            | ((unsigned long long)(unsigned)az1 << 17)
            | ((unsigned long long)(unsigned)iy1 << 12)
            | ((unsigned long long)(unsigned)iz1 << 7)
            | ((unsigned long long)(unsigned)sy  << 6)
            | ((unsigned long long)(unsigned)sz  << 5);
        unsigned fr1 = (p1 == p2) ? 2u : 1u;  // ref double-counts collapsed x

        {   // plane p1 entry
            float dx = rx - (float)p1;
            float dx2 = dx * dx;
            float a0 = dx2 + dy1s, a1 = dx2 + dy2s;
            unsigned m = 0;
            if (a0 + dz1s < 0.7569f) m |= 1u;
            if (a0 + dz2s < 0.7569f) m |= 2u;
            if (a1 + dz1s < 0.7569f) m |= 4u;
            if (a1 + dz2s < 0.7569f) m |= 8u;
            if (m) {
                unsigned ax = (unsigned)((int)rintf(dx * 2048.0f) + 2048);
                e1 = ((unsigned long long)ax << 43) | common
                   | ((unsigned long long)(fr1 - 1u) << 4) | m;
                put1 = true;
                r1 = atomicAdd(&h[p1], 1);
            }
        }
        if (p2 != p1) {
            float dx = rx - (float)p2;
            float dx2 = dx * dx;
            float a0 = dx2 + dy1s, a1 = dx2 + dy2s;
            unsigned m = 0;
            if (a0 + dz1s < 0.7569f) m |= 1u;
            if (a0 + dz2s < 0.7569f) m |= 2u;
            if (a1 + dz1s < 0.7569f) m |= 4u;
            if (a1 + dz2s < 0.7569f) m |= 8u;
            if (m) {
                unsigned ax = (unsigned)((int)rintf(dx * 2048.0f) + 2048);
                e2 = ((unsigned long long)ax << 43) | common | m;  // fr=1
                put2 = true;
                r2 = atomicAdd(&h[p2], 1);
            }
        }
    }
    __syncthreads();

    if (tid == 0) {
        int run = 0;
        #pragma unroll
        for (int p = 0; p < G; ++p) { offs[p] = run; run += h[p]; }
        offs[G] = run;
    }
    __syncthreads();

    if (put1) { int i1 = offs[p1] + r1; sp[i1] = e1; spl[i1] = (unsigned char)p1; }
    if (put2) { int i2 = offs[p2] + r2; sp[i2] = e2; spl[i2] = (unsigned char)p2; }
    if (tid < G) hist[c * G + tid] = h[tid];
    __syncthreads();

    const int T = offs[G];
    unsigned long long* chunk_pl = payload + (size_t)c * G * SUBCAP;
    for (int e = tid; e < T; e += 1024) {
        int p = spl[e];
        chunk_pl[(size_t)p * SUBCAP + (e - offs[p])] = sp[e];
    }
}

// K2: flat-index accumulate. Per bin: prefix the 49 chunk counts once, then a
// flat loop over all entries (i -> chunk via 6-step LDS binary search) at
// ~full lane utilization; integer decode + masked packed u64 LDS atomics.
__global__ __launch_bounds__(1024) void ge_accum(const unsigned long long* __restrict__ payload,
                                                 const int* __restrict__ hist,
                                                 const float* __restrict__ W,
                                                 const float* __restrict__ bias,
                                                 float* __restrict__ out) {
    __shared__ unsigned long long A[G2];       // 8 KB
    __shared__ int hc[NCHUNK_PER_B];
    __shared__ int choff[NCHUNK_PER_B + 1];
    const int tid = threadIdx.x;
    const int b = blockIdx.x >> 5;
    const int s = blockIdx.x & 31;

    A[tid] = 0ull;
    if (tid < NCHUNK_PER_B)
        hc[tid] = hist[(b * NCHUNK_PER_B + tid) * G + s];
    __syncthreads();
    if (tid == 0) {
        int run = 0;
        #pragma unroll
        for (int c = 0; c < NCHUNK_PER_B; ++c) { choff[c] = run; run += hc[c]; }
        choff[NCHUNK_PER_B] = run;
    }
    __syncthreads();

    const int total = choff[NCHUNK_PER_B];
    const unsigned long long* pb = payload + (size_t)b * NCHUNK_PER_B * G * SUBCAP;

    for (int i = tid; i < total; i += 1024) {
        // binary search: lo s.t. choff[lo] <= i < choff[lo+1]   (49 < 64 -> 6 steps)
        int lo = 0, hi = NCHUNK_PER_B;
        #pragma unroll
        for (int it = 0; it < 6; ++it) {
            int mid = (lo + hi) >> 1;
            if (i >= choff[mid]) lo = mid; else hi = mid;
        }
        unsigned long long e = pb[((size_t)lo * G + s) * SUBCAP + (i - choff[lo])];

        unsigned m   = (unsigned)e & 15u;
        unsigned fr  = 1u + (((unsigned)e >> 4) & 1u);
        int szi = ((int)e >> 5) & 1;
        int syi = ((int)e >> 6) & 1;
        int iz1 = ((int)e >> 7) & 31;
        int iy1 = ((int)e >> 12) & 31;
        unsigned az1 = (unsigned)(e >> 17) & 0x1FFFu;
        unsigned ay1 = (unsigned)(e >> 30) & 0x1FFFu;
        unsigned ax  = (unsigned)(e >> 43) & 0x1FFFu;

        unsigned long long base = ((unsigned long long)fr << 57)
                                | ((unsigned long long)(ax * fr) << 38);
        unsigned ayl = ay1 * fr, ayh = (ay1 - 2048u * syi) * fr;
        unsigned azl = az1 * fr, azh = (az1 - 2048u * szi) * fr;
        int cell = iy1 * G + iz1;

        if (m & 1u) atomicAdd(&A[cell],
            ((unsigned long long)ayl << 19) | azl | base);
        if (m & 2u) atomicAdd(&A[cell + szi],
            ((unsigned long long)ayl << 19) | azh | base);
        if (m & 4u) atomicAdd(&A[cell + G * syi],
            ((unsigned long long)ayh << 19) | azl | base);
        if (m & 8u) atomicAdd(&A[cell + G * syi + szi],
            ((unsigned long long)ayh << 19) | azh | base);
    }
    __syncthreads();

    const unsigned long long a = A[tid];
    const float cw  = (float)(unsigned)(a >> 57);
    const float fxs = (float)(unsigned)((a >> 38) & 0x7FFFFull);
    const float fys = (float)(unsigned)((a >> 19) & 0x7FFFFull);
    const float fzs = (float)(unsigned)( a         & 0x7FFFFull);
    const float kq = 1.0f / 2048.0f;
    const float sx = (fxs - 2048.0f * cw) * kq;
    const float sy = (fys - 2048.0f * cw) * kq;
    const float sz = (fzs - 2048.0f * cw) * kq;
    const float inv = 1.0f / fmaxf(cw, 1.0f);

    float* ob = out + (size_t)b * NC * G3 + (size_t)s * G2 + tid;
    #pragma unroll
    for (int ch = 0; ch < NC; ++ch) {
        float v = W[ch * 3 + 0] * sx + W[ch * 3 + 1] * sy + W[ch * 3 + 2] * sz
                + cw * bias[ch];
        ob[(size_t)ch * G3] = v * inv;
    }
}

// ---------- fallback: round-7 single kernel (used if ws too small) ----------
#define SEG 12288
#define QMAX SEG
__global__ __launch_bounds__(1024) void ge_fused(const float* __restrict__ x,
                                                 const float* __restrict__ W,
                                                 const float* __restrict__ bias,
                                                 float* __restrict__ out) {
    __shared__ float acc[G2][4];
    __shared__ int   q[QMAX];
    __shared__ int   qcount;
    const int b = blockIdx.x >> 5;
    const int s = blockIdx.x & 31;
    const float fs = (float)s;
    const int lane = threadIdx.x & 63;
    for (int i = threadIdx.x; i < G2 * 4; i += 1024) ((float*)acc)[i] = 0.0f;
    if (threadIdx.x == 0) qcount = 0;
    __syncthreads();
    const float* xb = x + (size_t)b * 3 * NPTS;
    for (int seg = 0; seg < NPTS; seg += SEG) {
        const int seg_end = (seg + SEG < NPTS) ? seg + SEG : NPTS;
        for (int base = seg; base < seg_end; base += 1024) {
            int n = base + threadIdx.x;
            bool pred = false; int tag = 0;
            if (n < seg_end) {
                float rx = (xb[n] + 0.5f) * 32.0f - 0.5f;
                int p1 = (int)fminf(fmaxf(floorf(rx), 0.0f), 31.0f);
                int p2 = (int)fminf(fmaxf(ceilf (rx), 0.0f), 31.0f);
                int reps = (p1 == s) + (p2 == s);
                pred = reps > 0;
                tag = n | (reps == 2 ? (int)0x80000000 : 0);
            }
            unsigned long long mask = __ballot(pred);
            int wcnt = __popcll(mask);
            if (wcnt) {
                int wbase = 0;
                if (lane == 0) wbase = atomicAdd(&qcount, wcnt);
                wbase = __shfl(wbase, 0);
                if (pred) q[wbase + __popcll(mask & ((1ULL << lane) - 1ULL))] = tag;
            }
        }
        __syncthreads();
        const int cnt = qcount;
        for (int i = threadIdx.x; i < cnt; i += 1024) {
            int e = q[i];
            int n = e & 0x7fffffff;
            float fr = (e < 0) ? 2.0f : 1.0f;
            float rx = (xb[n]          + 0.5f) * 32.0f - 0.5f;
            float ry = (xb[NPTS + n]   + 0.5f) * 32.0f - 0.5f;
            float rz = (xb[2*NPTS + n] + 0.5f) * 32.0f - 0.5f;
            float dx = rx - fs;
            float fy1 = fminf(fmaxf(floorf(ry), 0.0f), 31.0f);
            float fy2 = fminf(fmaxf(ceilf (ry), 0.0f), 31.0f);
            float fz1 = fminf(fmaxf(floorf(rz), 0.0f), 31.0f);
            float fz2 = fminf(fmaxf(ceilf (rz), 0.0f), 31.0f);
            #pragma unroll
            for (int cy = 0; cy < 2; ++cy) {
                float iy = cy ? fy2 : fy1;
                float dy = ry - iy;
                #pragma unroll
                for (int cz = 0; cz < 2; ++cz) {
                    float iz = cz ? fz2 : fz1;
                    float dz = rz - iz;
                    float d2 = dx * dx + dy * dy + dz * dz;
                    if (d2 < 0.7569f) {
                        int cell = (int)iy * G + (int)iz;
                        atomicAdd(&acc[cell][0], fr * dx);
                        atomicAdd(&acc[cell][1], fr * dy);
                        atomicAdd(&acc[cell][2], fr * dz);
                        atomicAdd(&acc[cell][3], fr);
                    }
                }
            }
        }
        __syncthreads();
        if (threadIdx.x == 0) qcount = 0;
        __syncthreads();
    }
    int cell = threadIdx.x;
    float sx = acc[cell][0], sy = acc[cell][1], sz = acc[cell][2], cnt = acc[cell][3];
    float inv = 1.0f / fmaxf(cnt, 1.0f);
    float* ob = out + (size_t)b * NC * G3 + (size_t)s * G2 + cell;
    #pragma unroll
    for (int c = 0; c < NC; ++c) {
        float v = W[c * 3 + 0] * sx + W[c * 3 + 1] * sy + W[c * 3 + 2] * sz
                + cnt * bias[c];
        ob[(size_t)c * G3] = v * inv;
    }
}

extern "C" void kernel_launch(void* const* d_in, const int* in_sizes, int n_in,
                              void* d_out, int out_size, void* d_ws, size_t ws_size,
                              hipStream_t stream) {
    const float* x    = (const float*)d_in[0];   // [8,3,50000]
    const float* W    = (const float*)d_in[1];   // [16,3]
    const float* bias = (const float*)d_in[2];   // [16]
    float* out = (float*)d_out;                  // [8,16,32,32,32]

    const size_t need = OFF_PAYLOAD
                      + (size_t)NCHUNK * G * SUBCAP * sizeof(unsigned long long);
    if (ws_size >= need) {
        char* wsb = (char*)d_ws;
        int* hist = (int*)(wsb + OFF_HIST);
        unsigned long long* payload = (unsigned long long*)(wsb + OFF_PAYLOAD);

        ge_bin  <<<dim3(NCHUNK_PER_B, NB), 1024, 0, stream>>>(x, hist, payload);
        ge_accum<<<NB * G, 1024, 0, stream>>>(payload, hist, W, bias, out);
    } else {
        ge_fused<<<NB * G, 1024, 0, stream>>>(x, W, bias, out);
    }
}